// Round 2
// baseline (430.307 us; speedup 1.0000x reference)
//
#include <hip/hip_runtime.h>
#include <stdint.h>

// Problem constants (reference: M,K,N = 8192,4096,4096)
#define GM 8192
#define GK 4096
#define GN 4096

typedef int v4i __attribute__((ext_vector_type(4)));

__device__ __forceinline__ void async_load16(const void* gptr, void* lptr) {
  __builtin_amdgcn_global_load_lds(
      (const __attribute__((address_space(1))) void*)gptr,
      (__attribute__((address_space(3))) void*)lptr,
      16 /*bytes*/, 0 /*offset*/, 0 /*aux*/);
}

// ---------------- Kernel 1: quantize x (fp32) -> int8 ----------------
// q = clamp(rint(x*scale + offset), -128, 127); rintf == half-even == jnp.round
__device__ __forceinline__ int quant_pack4(float4 f, float s, float o) {
  float a = fminf(fmaxf(rintf(f.x * s + o), -128.f), 127.f);
  float b = fminf(fmaxf(rintf(f.y * s + o), -128.f), 127.f);
  float c = fminf(fmaxf(rintf(f.z * s + o), -128.f), 127.f);
  float d = fminf(fmaxf(rintf(f.w * s + o), -128.f), 127.f);
  int ia = ((int)a) & 0xff, ib = ((int)b) & 0xff, ic = ((int)c) & 0xff, id = ((int)d) & 0xff;
  return ia | (ib << 8) | (ic << 16) | (id << 24);
}

__global__ __launch_bounds__(256) void quant_kernel(
    const float* __restrict__ x, int8_t* __restrict__ qx,
    const float* __restrict__ scale_p, const float* __restrict__ off_p, int n16) {
  int i = blockIdx.x * 256 + threadIdx.x;
  if (i >= n16) return;
  float s = scale_p[0], o = off_p[0];
  const float4* xp = (const float4*)x + (size_t)i * 4;
  v4i out;
  out.x = quant_pack4(xp[0], s, o);
  out.y = quant_pack4(xp[1], s, o);
  out.z = quant_pack4(xp[2], s, o);
  out.w = quant_pack4(xp[3], s, o);
  ((v4i*)qx)[i] = out;
}

// ---------------- Kernel 2: transpose q_weight [K][N] (INT32 storage!) -> Bt [N][K] int8
// Harness marshals integer inputs as int32 arrays: q_weight arrives as 4 B/elem.
__global__ __launch_bounds__(256) void transpose_kernel(
    const int* __restrict__ B, int8_t* __restrict__ Bt) {
  __shared__ int8_t tile[64][68];  // +4 pad to spread banks on column reads
  const int t = threadIdx.x;
  const int n0 = blockIdx.x * 64;
  const int k0 = blockIdx.y * 64;
#pragma unroll
  for (int r = 0; r < 4; ++r) {
    int kl = r * 16 + (t >> 4);
    int nl = (t & 15) * 4;
    int4 v = *(const int4*)(B + (size_t)(k0 + kl) * GN + n0 + nl);
    tile[kl][nl + 0] = (int8_t)v.x;
    tile[kl][nl + 1] = (int8_t)v.y;
    tile[kl][nl + 2] = (int8_t)v.z;
    tile[kl][nl + 3] = (int8_t)v.w;
  }
  __syncthreads();
#pragma unroll
  for (int r = 0; r < 4; ++r) {
    int nl = r * 16 + (t >> 4);
    int k4 = (t & 15) * 4;
    char4 v;
    v.x = tile[k4 + 0][nl];
    v.y = tile[k4 + 1][nl];
    v.z = tile[k4 + 2][nl];
    v.w = tile[k4 + 3][nl];
    *(char4*)(Bt + (size_t)(n0 + nl) * GK + k0 + k4) = v;
  }
}

// ---------------- Kernel 3: int8 GEMM, 128x128 tile, mfma_i32_16x16x64_i8 --------
// A = qx [M][K] row-major, Bt [N][K] row-major (both k-contiguous -> m97 gemm_bt form)
// C[m][n] = (sum_k A[m][k]*Bt[n][k] + bias[n]) * deq[n]
__global__ __launch_bounds__(256) void gemm_i8_kernel(
    const int8_t* __restrict__ A, const int8_t* __restrict__ Bt,
    const int* __restrict__ bias, const float* __restrict__ deq,
    float* __restrict__ C) {
  __shared__ __align__(16) int8_t Alds[128 * 64];  // 8 KB, row m stride 64
  __shared__ __align__(16) int8_t Blds[128 * 64];  // 8 KB, row n stride 64

  const int t = threadIdx.x;
  const int lane = t & 63;
  const int wave = t >> 6;
  const int m0 = blockIdx.y * 128;
  const int n0 = blockIdx.x * 128;
  const int wm = (wave >> 1) * 64;  // wave's 64-row sub-tile
  const int wn = (wave & 1) * 64;   // wave's 64-col sub-tile

  v4i acc[4][4];
  const v4i vzero = {0, 0, 0, 0};
#pragma unroll
  for (int mi = 0; mi < 4; ++mi)
#pragma unroll
    for (int ni = 0; ni < 4; ++ni) acc[mi][ni] = vzero;

  // Staging: thread t loads 16 B of row (t>>2), byte offset (t&3)*16.
  // LDS dest = t*16  ->  wave-uniform base + lane*16 (global_load_lds constraint).
  const int srow = t >> 2;
  const int scol = (t & 3) * 16;
  const int8_t* ag0 = A + (size_t)(m0 + srow) * GK + scol;
  const int8_t* ag1 = ag0 + (size_t)64 * GK;
  const int8_t* bg0 = Bt + (size_t)(n0 + srow) * GK + scol;
  const int8_t* bg1 = bg0 + (size_t)64 * GK;
  int8_t* al0 = Alds + t * 16;
  int8_t* al1 = al0 + 64 * 64;
  int8_t* bl0 = Blds + t * 16;
  int8_t* bl1 = bl0 + 64 * 64;

  // Fragment address pieces: A-op m = lane&15, k = (lane>>4)*16 + j (j=0..15)
  const int fr = lane & 15;
  const int kg = (lane >> 4) * 16;

  for (int k0 = 0; k0 < GK; k0 += 64) {
    __syncthreads();  // prev iteration's readers done before overwrite
    async_load16(ag0 + k0, al0);
    async_load16(ag1 + k0, al1);
    async_load16(bg0 + k0, bl0);
    async_load16(bg1 + k0, bl1);
    __syncthreads();  // emits s_waitcnt vmcnt(0) -> LDS tiles ready

    v4i af[4], bf[4];
#pragma unroll
    for (int i = 0; i < 4; ++i) {
      af[i] = *(const v4i*)(Alds + (size_t)(wm + i * 16 + fr) * 64 + kg);
      bf[i] = *(const v4i*)(Blds + (size_t)(wn + i * 16 + fr) * 64 + kg);
    }
#pragma unroll
    for (int mi = 0; mi < 4; ++mi)
#pragma unroll
      for (int ni = 0; ni < 4; ++ni)
        acc[mi][ni] =
            __builtin_amdgcn_mfma_i32_16x16x64_i8(af[mi], bf[ni], acc[mi][ni], 0, 0, 0);
  }

  // Epilogue. C/D layout: col = lane&15, row = (lane>>4)*4 + reg  [m89-verified]
  const int col = lane & 15;
  const int rq = (lane >> 4) * 4;
#pragma unroll
  for (int ni = 0; ni < 4; ++ni) {
    const int gc = n0 + wn + ni * 16 + col;
    const float d = deq[gc];
    const int bs = bias[gc];
#pragma unroll
    for (int mi = 0; mi < 4; ++mi) {
      const int gr = m0 + wm + mi * 16 + rq;
#pragma unroll
      for (int r = 0; r < 4; ++r)
        C[(size_t)(gr + r) * GN + gc] = (float)(acc[mi][ni][r] + bs) * d;
    }
  }
}

extern "C" void kernel_launch(void* const* d_in, const int* in_sizes, int n_in,
                              void* d_out, int out_size, void* d_ws, size_t ws_size,
                              hipStream_t stream) {
  const float* x = (const float*)d_in[0];
  const int* qw = (const int*)d_in[1];        // int8 in reference -> int32 on device
  const float* act_scale = (const float*)d_in[2];
  const float* act_offset = (const float*)d_in[3];
  const float* deq = (const float*)d_in[4];
  const int* bias = (const int*)d_in[5];
  float* out = (float*)d_out;

  // Workspace: qx [M*K int8] then Bt [N*K int8]  (48 MB total)
  int8_t* qx = (int8_t*)d_ws;
  int8_t* Bt = (int8_t*)d_ws + (size_t)GM * GK;

  const int n16 = GM * GK / 16;
  quant_kernel<<<(n16 + 255) / 256, 256, 0, stream>>>(x, qx, act_scale, act_offset, n16);
  transpose_kernel<<<dim3(GN / 64, GK / 64), 256, 0, stream>>>(qw, Bt);
  gemm_i8_kernel<<<dim3(GN / 128, GM / 128), 256, 0, stream>>>(qx, Bt, bias, deq, out);
}

// Round 3
// 422.447 us; speedup vs baseline: 1.0186x; 1.0186x over previous
//
#include <hip/hip_runtime.h>
#include <stdint.h>

// Problem constants (reference: M,K,N = 8192,4096,4096)
#define GM 8192
#define GK 4096
#define GN 4096

typedef int v4i __attribute__((ext_vector_type(4)));

__device__ __forceinline__ void async_load16(const void* gptr, void* lptr) {
  __builtin_amdgcn_global_load_lds(
      (const __attribute__((address_space(1))) void*)gptr,
      (__attribute__((address_space(3))) void*)lptr,
      16 /*bytes*/, 0 /*offset*/, 0 /*aux*/);
}

// ---------------- Kernel 1: quantize x (fp32) -> int8 ----------------
// q = clamp(rint(x*scale + offset), -128, 127); rintf == half-even == jnp.round
// Thread i handles float4 i: wave reads 1024 B contiguous, writes 256 B contiguous.
__global__ __launch_bounds__(256) void quant_kernel(
    const float* __restrict__ x, int8_t* __restrict__ qx,
    const float* __restrict__ scale_p, const float* __restrict__ off_p) {
  const int i = blockIdx.x * 256 + threadIdx.x;  // grid sized exactly: no bounds check
  const float s = scale_p[0], o = off_p[0];
  const float4 f = ((const float4*)x)[i];
  float a = fminf(fmaxf(rintf(f.x * s + o), -128.f), 127.f);
  float b = fminf(fmaxf(rintf(f.y * s + o), -128.f), 127.f);
  float c = fminf(fmaxf(rintf(f.z * s + o), -128.f), 127.f);
  float d = fminf(fmaxf(rintf(f.w * s + o), -128.f), 127.f);
  int packed = (((int)a) & 0xff) | ((((int)b) & 0xff) << 8) |
               ((((int)c) & 0xff) << 16) | ((((int)d) & 0xff) << 24);
  ((int*)qx)[i] = packed;
}

// ---------------- Kernel 2: transpose q_weight [K][N] (int32 storage) -> Bt [N][K] int8
// Harness marshals integer inputs as int32: q_weight arrives 4 B/elem.
// int32-granular transpose through LDS (pad 65 -> <=2-way conflicts, free),
// output side emits 16 B int4 stores, fully coalesced.
__global__ __launch_bounds__(256) void transpose_kernel(
    const int* __restrict__ B, int8_t* __restrict__ Bt) {
  __shared__ int tile32[64][65];
  const int t = threadIdx.x;
  const int n0 = blockIdx.x * 64;
  const int k0 = blockIdx.y * 64;
  // Load: 64x64 int32 tile, 16 B per lane, contiguous 4 KB per (iter, 16-row group)
#pragma unroll
  for (int r = 0; r < 4; ++r) {
    const int kl = r * 16 + (t >> 4);
    const int nl = (t & 15) * 4;
    const int4 v = *(const int4*)(B + (size_t)(k0 + kl) * GN + n0 + nl);
    *(int4*)&tile32[kl][nl] = v;
  }
  __syncthreads();
  // Store: thread emits 16 k-bytes of one n-row: Bt[n0+nl][k0+kc .. +15]
  const int nl = t >> 2;
  const int kc = (t & 3) * 16;
  v4i out;
#pragma unroll
  for (int w = 0; w < 4; ++w) {
    int p = 0;
#pragma unroll
    for (int j = 0; j < 4; ++j)
      p |= (tile32[kc + w * 4 + j][nl] & 0xff) << (8 * j);
    out[w] = p;
  }
  *(v4i*)(Bt + (size_t)(n0 + nl) * GK + k0 + kc) = out;
}

// ---------------- Kernel 3: int8 GEMM, 128x128 tile, mfma_i32_16x16x64_i8 --------
// A = qx [M][K] row-major, Bt [N][K] row-major (both k-contiguous -> m97 gemm_bt form)
// C[m][n] = (sum_k A[m][k]*Bt[n][k] + bias[n]) * deq[n]
__global__ __launch_bounds__(256) void gemm_i8_kernel(
    const int8_t* __restrict__ A, const int8_t* __restrict__ Bt,
    const int* __restrict__ bias, const float* __restrict__ deq,
    float* __restrict__ C) {
  __shared__ __align__(16) int8_t Alds[128 * 64];  // 8 KB, row m stride 64
  __shared__ __align__(16) int8_t Blds[128 * 64];  // 8 KB, row n stride 64

  const int t = threadIdx.x;
  const int lane = t & 63;
  const int wave = t >> 6;
  const int m0 = blockIdx.y * 128;
  const int n0 = blockIdx.x * 128;
  const int wm = (wave >> 1) * 64;  // wave's 64-row sub-tile
  const int wn = (wave & 1) * 64;   // wave's 64-col sub-tile

  v4i acc[4][4];
  const v4i vzero = {0, 0, 0, 0};
#pragma unroll
  for (int mi = 0; mi < 4; ++mi)
#pragma unroll
    for (int ni = 0; ni < 4; ++ni) acc[mi][ni] = vzero;

  // Staging: thread t loads 16 B of row (t>>2), byte offset (t&3)*16.
  // LDS dest = t*16  ->  wave-uniform base + lane*16 (global_load_lds constraint).
  const int srow = t >> 2;
  const int scol = (t & 3) * 16;
  const int8_t* ag0 = A + (size_t)(m0 + srow) * GK + scol;
  const int8_t* ag1 = ag0 + (size_t)64 * GK;
  const int8_t* bg0 = Bt + (size_t)(n0 + srow) * GK + scol;
  const int8_t* bg1 = bg0 + (size_t)64 * GK;
  int8_t* al0 = Alds + t * 16;
  int8_t* al1 = al0 + 64 * 64;
  int8_t* bl0 = Blds + t * 16;
  int8_t* bl1 = bl0 + 64 * 64;

  // Fragment address pieces: A-op m = lane&15, k = (lane>>4)*16 + j (j=0..15)
  const int fr = lane & 15;
  const int kg = (lane >> 4) * 16;

  for (int k0 = 0; k0 < GK; k0 += 64) {
    __syncthreads();  // prev iteration's readers done before overwrite
    async_load16(ag0 + k0, al0);
    async_load16(ag1 + k0, al1);
    async_load16(bg0 + k0, bl0);
    async_load16(bg1 + k0, bl1);
    __syncthreads();  // emits s_waitcnt vmcnt(0) -> LDS tiles ready

    v4i af[4], bf[4];
#pragma unroll
    for (int i = 0; i < 4; ++i) {
      af[i] = *(const v4i*)(Alds + (size_t)(wm + i * 16 + fr) * 64 + kg);
      bf[i] = *(const v4i*)(Blds + (size_t)(wn + i * 16 + fr) * 64 + kg);
    }
#pragma unroll
    for (int mi = 0; mi < 4; ++mi)
#pragma unroll
      for (int ni = 0; ni < 4; ++ni)
        acc[mi][ni] =
            __builtin_amdgcn_mfma_i32_16x16x64_i8(af[mi], bf[ni], acc[mi][ni], 0, 0, 0);
  }

  // Epilogue. C/D layout: col = lane&15, row = (lane>>4)*4 + reg  [m89-verified]
  const int col = lane & 15;
  const int rq = (lane >> 4) * 4;
#pragma unroll
  for (int ni = 0; ni < 4; ++ni) {
    const int gc = n0 + wn + ni * 16 + col;
    const float d = deq[gc];
    const int bs = bias[gc];
#pragma unroll
    for (int mi = 0; mi < 4; ++mi) {
      const int gr = m0 + wm + mi * 16 + rq;
#pragma unroll
      for (int r = 0; r < 4; ++r)
        C[(size_t)(gr + r) * GN + gc] = (float)(acc[mi][ni][r] + bs) * d;
    }
  }
}

extern "C" void kernel_launch(void* const* d_in, const int* in_sizes, int n_in,
                              void* d_out, int out_size, void* d_ws, size_t ws_size,
                              hipStream_t stream) {
  const float* x = (const float*)d_in[0];
  const int* qw = (const int*)d_in[1];        // int8 in reference -> int32 on device
  const float* act_scale = (const float*)d_in[2];
  const float* act_offset = (const float*)d_in[3];
  const float* deq = (const float*)d_in[4];
  const int* bias = (const int*)d_in[5];
  float* out = (float*)d_out;

  // Workspace: qx [M*K int8] then Bt [N*K int8]  (48 MB total)
  int8_t* qx = (int8_t*)d_ws;
  int8_t* Bt = (int8_t*)d_ws + (size_t)GM * GK;

  const int n4 = GM * GK / 4;  // one float4 per thread
  quant_kernel<<<n4 / 256, 256, 0, stream>>>(x, qx, act_scale, act_offset);
  transpose_kernel<<<dim3(GN / 64, GK / 64), 256, 0, stream>>>(qw, Bt);
  gemm_i8_kernel<<<dim3(GN / 128, GM / 128), 256, 0, stream>>>(qx, Bt, bias, deq, out);
}

// Round 4
// 411.277 us; speedup vs baseline: 1.0463x; 1.0272x over previous
//
#include <hip/hip_runtime.h>
#include <stdint.h>

// Problem constants (reference: M,K,N = 8192,4096,4096)
#define GM 8192
#define GK 4096
#define GN 4096

typedef int v4i __attribute__((ext_vector_type(4)));

__device__ __forceinline__ void async_load16(const void* gptr, void* lptr) {
  __builtin_amdgcn_global_load_lds(
      (const __attribute__((address_space(1))) void*)gptr,
      (__attribute__((address_space(3))) void*)lptr,
      16 /*bytes*/, 0 /*offset*/, 0 /*aux*/);
}

// ---------------- Kernel 1: fused prep ----------------
// Blocks [0, TBLK): transpose q_weight [K][N] (int32 storage) -> Bt [N][K] int8.
// Blocks [TBLK, TBLK+QBLK): quantize x (fp32) -> qx int8.
// Fused so both memory streams run concurrently (independent work).
#define TBLK ((GN / 64) * (GK / 64))      // 4096 transpose blocks
#define QBLK (GM * GK / 4 / 256)          // 32768 quant blocks (one float4/thread)

__global__ __launch_bounds__(256) void prep_kernel(
    const float* __restrict__ x, int8_t* __restrict__ qx,
    const float* __restrict__ scale_p, const float* __restrict__ off_p,
    const int* __restrict__ B, int8_t* __restrict__ Bt) {
  __shared__ int tile32[64][65];
  const int b = blockIdx.x;
  const int t = threadIdx.x;
  if (b < TBLK) {
    // ---- transpose path: int32-granular through LDS, 16 B coalesced stores ----
    const int n0 = (b & 63) * 64;
    const int k0 = (b >> 6) * 64;
#pragma unroll
    for (int r = 0; r < 4; ++r) {
      const int kl = r * 16 + (t >> 4);
      const int nl = (t & 15) * 4;
      const int4 v = *(const int4*)(B + (size_t)(k0 + kl) * GN + n0 + nl);
      *(int4*)&tile32[kl][nl] = v;
    }
    __syncthreads();
    const int nl = t >> 2;
    const int kc = (t & 3) * 16;
    v4i out;
#pragma unroll
    for (int w = 0; w < 4; ++w) {
      int p = 0;
#pragma unroll
      for (int j = 0; j < 4; ++j)
        p |= (tile32[kc + w * 4 + j][nl] & 0xff) << (8 * j);
      out[w] = p;
    }
    *(v4i*)(Bt + (size_t)(n0 + nl) * GK + k0 + kc) = out;
  } else {
    // ---- quant path: q = clamp(rint(x*s + o), -128, 127), rintf == half-even ----
    const int i = (b - TBLK) * 256 + t;
    const float s = scale_p[0], o = off_p[0];
    const float4 f = ((const float4*)x)[i];
    float a0 = fminf(fmaxf(rintf(f.x * s + o), -128.f), 127.f);
    float b0 = fminf(fmaxf(rintf(f.y * s + o), -128.f), 127.f);
    float c0 = fminf(fmaxf(rintf(f.z * s + o), -128.f), 127.f);
    float d0 = fminf(fmaxf(rintf(f.w * s + o), -128.f), 127.f);
    int packed = (((int)a0) & 0xff) | ((((int)b0) & 0xff) << 8) |
                 ((((int)c0) & 0xff) << 16) | ((((int)d0) & 0xff) << 24);
    ((int*)qx)[i] = packed;
  }
}

// ---------------- Kernel 2: int8 GEMM, 128x128 tile, BK=128, mfma_i32_16x16x64_i8
// A = qx [M][K] row-major, Bt [N][K] row-major (both k-contiguous).
// BK=128 as TWO k-half LDS buffers of row-stride 64 each: halves the barrier
// count (64 -> 32 iterations) without changing the global_load_lds dest
// pattern (base + t*16) or the per-read LDS bank profile. 32 KB LDS total.
// C[m][n] = (sum_k A[m][k]*Bt[n][k] + bias[n]) * deq[n]
__global__ __launch_bounds__(256) void gemm_i8_kernel(
    const int8_t* __restrict__ A, const int8_t* __restrict__ Bt,
    const int* __restrict__ bias, const float* __restrict__ deq,
    float* __restrict__ C) {
  // [half][row][64] ; half h covers k in [h*64, h*64+64)
  __shared__ __align__(16) int8_t Alds[2][128 * 64];  // 16 KB
  __shared__ __align__(16) int8_t Blds[2][128 * 64];  // 16 KB

  const int t = threadIdx.x;
  const int lane = t & 63;
  const int wave = t >> 6;
  const int m0 = blockIdx.y * 128;
  const int n0 = blockIdx.x * 128;
  const int wm = (wave >> 1) * 64;  // wave's 64-row sub-tile
  const int wn = (wave & 1) * 64;   // wave's 64-col sub-tile

  v4i acc[4][4];
  const v4i vzero = {0, 0, 0, 0};
#pragma unroll
  for (int mi = 0; mi < 4; ++mi)
#pragma unroll
    for (int ni = 0; ni < 4; ++ni) acc[mi][ni] = vzero;

  // Staging: thread t covers row (t>>2), 16 B at col (t&3)*16 of each k-half.
  // LDS dest = half_base + rowgroup*4096 + t*16  (wave-uniform + lane*16).
  const int srow = t >> 2;
  const int scol = (t & 3) * 16;
  const int8_t* ag = A + (size_t)(m0 + srow) * GK + scol;   // row group 0
  const int8_t* bg = Bt + (size_t)(n0 + srow) * GK + scol;
  const size_t rg = (size_t)64 * GK;                        // +64 rows in global
  int8_t* al = &Alds[0][0] + t * 16;
  int8_t* bl = &Blds[0][0] + t * 16;

  // Fragment address pieces: A-op m = lane&15, k = (lane>>4)*16 + j (j=0..15)
  const int fr = lane & 15;
  const int kg = (lane >> 4) * 16;

  for (int k0 = 0; k0 < GK; k0 += 128) {
    __syncthreads();  // prev iteration's readers done before overwrite
    // k-half 0 (cols k0..k0+63)
    async_load16(ag + k0, al);                     // rows 0..63   -> Alds[0] lo
    async_load16(ag + rg + k0, al + 4096);         // rows 64..127 -> Alds[0] hi
    async_load16(bg + k0, bl);
    async_load16(bg + rg + k0, bl + 4096);
    // k-half 1 (cols k0+64..k0+127)
    async_load16(ag + k0 + 64, al + 8192);         // -> Alds[1] lo
    async_load16(ag + rg + k0 + 64, al + 12288);   // -> Alds[1] hi
    async_load16(bg + k0 + 64, bl + 8192);
    async_load16(bg + rg + k0 + 64, bl + 12288);
    __syncthreads();  // s_waitcnt vmcnt(0) -> both k-halves resident

#pragma unroll
    for (int s = 0; s < 2; ++s) {
      v4i af[4], bf[4];
#pragma unroll
      for (int i = 0; i < 4; ++i) {
        af[i] = *(const v4i*)(&Alds[s][0] + (size_t)(wm + i * 16 + fr) * 64 + kg);
        bf[i] = *(const v4i*)(&Blds[s][0] + (size_t)(wn + i * 16 + fr) * 64 + kg);
      }
#pragma unroll
      for (int mi = 0; mi < 4; ++mi)
#pragma unroll
        for (int ni = 0; ni < 4; ++ni)
          acc[mi][ni] =
              __builtin_amdgcn_mfma_i32_16x16x64_i8(af[mi], bf[ni], acc[mi][ni], 0, 0, 0);
    }
  }

  // Epilogue. C/D layout: col = lane&15, row = (lane>>4)*4 + reg  [m89-verified]
  const int col = lane & 15;
  const int rq = (lane >> 4) * 4;
#pragma unroll
  for (int ni = 0; ni < 4; ++ni) {
    const int gc = n0 + wn + ni * 16 + col;
    const float d = deq[gc];
    const int bs = bias[gc];
#pragma unroll
    for (int mi = 0; mi < 4; ++mi) {
      const int gr = m0 + wm + mi * 16 + rq;
#pragma unroll
      for (int r = 0; r < 4; ++r)
        C[(size_t)(gr + r) * GN + gc] = (float)(acc[mi][ni][r] + bs) * d;
    }
  }
}

extern "C" void kernel_launch(void* const* d_in, const int* in_sizes, int n_in,
                              void* d_out, int out_size, void* d_ws, size_t ws_size,
                              hipStream_t stream) {
  const float* x = (const float*)d_in[0];
  const int* qw = (const int*)d_in[1];        // int8 in reference -> int32 on device
  const float* act_scale = (const float*)d_in[2];
  const float* act_offset = (const float*)d_in[3];
  const float* deq = (const float*)d_in[4];
  const int* bias = (const int*)d_in[5];
  float* out = (float*)d_out;

  // Workspace: qx [M*K int8] then Bt [N*K int8]  (48 MB total)
  int8_t* qx = (int8_t*)d_ws;
  int8_t* Bt = (int8_t*)d_ws + (size_t)GM * GK;

  prep_kernel<<<TBLK + QBLK, 256, 0, stream>>>(x, qx, act_scale, act_offset, qw, Bt);
  gemm_i8_kernel<<<dim3(GN / 128, GM / 128), 256, 0, stream>>>(qx, Bt, bias, deq, out);
}